// Round 6
// baseline (249.913 us; speedup 1.0000x reference)
//
#include <hip/hip_runtime.h>
#include <hip/hip_bf16.h>

// LiteMLA: B=8, C=256, H=W=64, N=HW=4096, td=256, d=8, heads=64
// ws: qkv bf16 (8,768,4096) | agg bf16 (8,768,4096) | att_f bf16 (8,64,4096,8)
//     | w_projbf bf16 (256,512) | kvb f32 (8,64,72)
// kv partials (4 chunks x 36864 f32) live in the att_f region (written later).
// Pipeline: prep_w, qkv_gemm (MFMA), dw_agg (split-ch f32 LDS, scalar-pipe
//           weights), kv_pass (4-way n-split), kv_red, att_pass (reg-kv),
//           proj_gemm (LDS-free MFMA)

#define HW 4096
#define ATT_EPS 1e-15f
#define BN_EPS 1e-6f

typedef __attribute__((ext_vector_type(8))) short short8;
typedef __attribute__((ext_vector_type(4))) short short4v;
typedef __attribute__((ext_vector_type(4))) float f32x4;
typedef __attribute__((ext_vector_type(2))) float f32x2;
typedef __attribute__((ext_vector_type(8))) unsigned short u16x8;
typedef __attribute__((ext_vector_type(4))) unsigned short u16x4;

static __device__ inline short f2bf(float f) {
    union { float f; unsigned u; } v; v.f = f;
    unsigned r = v.u + 0x7fff + ((v.u >> 16) & 1);   // RNE, finite inputs
    return (short)(r >> 16);
}
static __device__ inline float bf2f(unsigned short u) {
    union { unsigned u; float f; } v; v.u = (unsigned)u << 16; return v.f;
}

// ---------------- K0: w_proj f32 -> bf16 (256x512) ----------------
__global__ __launch_bounds__(256) void prep_w(const float* __restrict__ wproj,
                                              unsigned short* __restrict__ wbf) {
    const int i = (blockIdx.x * 256 + threadIdx.x) * 4;
    float4 v = *(const float4*)&wproj[i];
    u16x4 r = {(unsigned short)f2bf(v.x), (unsigned short)f2bf(v.y),
               (unsigned short)f2bf(v.z), (unsigned short)f2bf(v.w)};
    *(u16x4*)&wbf[i] = r;
}

// ---------------- K1: qkv(bf16) = W(768x256) @ X(256x4096), bf16 MFMA --------
__global__ __launch_bounds__(256) void qkv_gemm(const float* __restrict__ x,
                                                const float* __restrict__ w,
                                                unsigned short* __restrict__ qkv) {
    __shared__ short A_l[128 * 40];
    __shared__ short B_l[128 * 40];
    const int t  = threadIdx.x;
    const int b  = blockIdx.z;
    const int ob = blockIdx.y * 128;
    const int nb = blockIdx.x * 128;
    const float* xb = x + (size_t)b * 256 * HW;

    const int lane = t & 63, wave = t >> 6;
    const int wo = (wave >> 1) * 64, wn = (wave & 1) * 64;

    f32x4 acc[4][4];
#pragma unroll
    for (int s = 0; s < 4; s++)
#pragma unroll
        for (int u = 0; u < 4; u++) acc[s][u] = (f32x4){0.f, 0.f, 0.f, 0.f};

    const int col4 = (t & 7) * 4;
    const int r0   = t >> 3;            // 0..31
    for (int kb = 0; kb < 256; kb += 32) {
        __syncthreads();
#pragma unroll
        for (int i = 0; i < 4; i++) {
            const int r = r0 + 32 * i;
            float4 v = *(const float4*)&w[(ob + r) * 256 + kb + col4];
            short4v s4 = {f2bf(v.x), f2bf(v.y), f2bf(v.z), f2bf(v.w)};
            *(short4v*)&A_l[r * 40 + col4] = s4;
        }
#pragma unroll
        for (int i = 0; i < 4; i++) {
            const int n4 = (t & 7) + 8 * i;
            float4 v = *(const float4*)&xb[(size_t)(kb + r0) * HW + nb + n4 * 4];
            B_l[(n4 * 4 + 0) * 40 + r0] = f2bf(v.x);
            B_l[(n4 * 4 + 1) * 40 + r0] = f2bf(v.y);
            B_l[(n4 * 4 + 2) * 40 + r0] = f2bf(v.z);
            B_l[(n4 * 4 + 3) * 40 + r0] = f2bf(v.w);
        }
        __syncthreads();

        short8 af[4], bf[4];
#pragma unroll
        for (int s = 0; s < 4; s++)
            af[s] = *(const short8*)&A_l[(wo + s * 16 + (lane & 15)) * 40 + (lane >> 4) * 8];
#pragma unroll
        for (int u = 0; u < 4; u++)
            bf[u] = *(const short8*)&B_l[(wn + u * 16 + (lane & 15)) * 40 + (lane >> 4) * 8];
#pragma unroll
        for (int s = 0; s < 4; s++)
#pragma unroll
            for (int u = 0; u < 4; u++)
                acc[s][u] = __builtin_amdgcn_mfma_f32_16x16x32_bf16(af[s], bf[u], acc[s][u], 0, 0, 0);
    }

#pragma unroll
    for (int s = 0; s < 4; s++)
#pragma unroll
        for (int u = 0; u < 4; u++)
#pragma unroll
            for (int r = 0; r < 4; r++) {
                const int o = ob + wo + s * 16 + (lane >> 4) * 4 + r;
                const int n = nb + wn + u * 16 + (lane & 15);
                qkv[((size_t)b * 768 + o) * HW + n] = (unsigned short)f2bf(acc[s][u][r]);
            }
}

// ---------------- K2: fused dw5x5 + pw8x8 ------------------------------------
// grid (4 ytiles(16 rows), 96 g, 8 b), block 256. Thread: 1 row x 4 col.
// Weights via block-uniform global pointers -> scalar pipe (R5 win: zero LDS
// traffic for weights). Tile f32 [4ch][20r][64c] split 2x with refill
// (20.7 KB -> 6 blocks/CU). Accumulator out[8][4] = 32 f32 (R2: bigger spills).
__global__ __launch_bounds__(256, 6) void dw_agg(const unsigned short* __restrict__ qkv,
                                                 const float* __restrict__ wdw,
                                                 const float* __restrict__ wpw,
                                                 unsigned short* __restrict__ agg) {
    __shared__ float tile_raw[8 + 4 * 20 * 64 + 8];   // 20.7 KB
    float* tile = tile_raw + 8;
    const int b = blockIdx.z, g = blockIdx.y;
    const int y0 = blockIdx.x * 16;
    const int t = threadIdx.x;
    const int tx = t & 15, ty = t >> 4;     // col-quad, output row

    const float* wkg = wdw + g * 8 * 25;    // block-uniform -> scalar loads
    const float* pwg = wpw + g * 64;        // block-uniform -> scalar loads

    float out[8][4];
#pragma unroll
    for (int o = 0; o < 8; o++)
#pragma unroll
        for (int j = 0; j < 4; j++) out[o][j] = 0.f;

#pragma unroll 1
    for (int half = 0; half < 2; half++) {
        if (half) __syncthreads();          // all reads of prev half done
        // fill: 640 octet-slots (4ch x 20r x 8 col-octets); bf16->f32 once.
#pragma unroll
        for (int k = 0; k < 3; k++) {
            const int i = t + 256 * k;
            if (i < 640) {
                const int c8 = i & 7, rr = (i >> 3) % 20, ch = i / 160;
                const int y = y0 - 2 + rr;
                u16x8 v = {0, 0, 0, 0, 0, 0, 0, 0};
                if (y >= 0 && y < 64)
                    v = *(const u16x8*)&qkv[((size_t)(b * 768 + g * 8 + half * 4 + ch)) * HW + y * 64 + c8 * 8];
                f32x4 lo = {bf2f(v[0]), bf2f(v[1]), bf2f(v[2]), bf2f(v[3])};
                f32x4 hi = {bf2f(v[4]), bf2f(v[5]), bf2f(v[6]), bf2f(v[7])};
                *(f32x4*)&tile[i * 8]     = lo;
                *(f32x4*)&tile[i * 8 + 4] = hi;
            }
        }
        __syncthreads();

#pragma unroll 1
        for (int ch4 = 0; ch4 < 4; ch4++) {
            const int ch = half * 4 + ch4;
            const float* wkc = wkg + ch * 25;    // uniform -> SGPR
            float a0 = 0.f, a1 = 0.f, a2 = 0.f, a3 = 0.f;
#pragma unroll
            for (int dy = 0; dy < 5; dy++) {
                const int off = ch4 * 1280 + (ty + dy) * 64 + tx * 4;
                f32x4 C = *(const f32x4*)&tile[off];        // ds_read_b128
                f32x2 L = *(const f32x2*)&tile[off - 2];    // ds_read_b64
                f32x2 R = *(const f32x2*)&tile[off + 4];    // ds_read_b64
                float win[8];
                win[0] = (tx == 0)  ? 0.f : L[0];
                win[1] = (tx == 0)  ? 0.f : L[1];
                win[2] = C[0]; win[3] = C[1];
                win[4] = C[2]; win[5] = C[3];
                win[6] = (tx == 15) ? 0.f : R[0];
                win[7] = (tx == 15) ? 0.f : R[1];
#pragma unroll
                for (int dx = 0; dx < 5; dx++) {
                    const float wv = wkc[dy * 5 + dx];      // SGPR operand
                    a0 += wv * win[dx + 0];
                    a1 += wv * win[dx + 1];
                    a2 += wv * win[dx + 2];
                    a3 += wv * win[dx + 3];
                }
            }
#pragma unroll
            for (int o = 0; o < 8; o++) {
                const float wv = pwg[o * 8 + ch];           // SGPR operand
                out[o][0] += wv * a0; out[o][1] += wv * a1;
                out[o][2] += wv * a2; out[o][3] += wv * a3;
            }
        }
    }

#pragma unroll
    for (int o = 0; o < 8; o++) {
        u16x4 rv = {(unsigned short)f2bf(out[o][0]), (unsigned short)f2bf(out[o][1]),
                    (unsigned short)f2bf(out[o][2]), (unsigned short)f2bf(out[o][3])};
        *(u16x4*)&agg[((size_t)(b * 768 + g * 8 + o)) * HW + (y0 + ty) * 64 + tx * 4] = rv;
    }
}

// ---------------- K3: kv partials, 4-way n-split -----------------------------
// R5 counters: 2 blocks/CU, HBM 8%, VALU 14% -> pure latency starvation.
// grid (64 h, 8 b, 4 chunks) = 2048 blocks; each thread reduces ONE u16x4
// group (4 px). Partials written to kvpart[c][bh][72] (lives in att_f region,
// overwritten only later by att_pass).
__global__ __launch_bounds__(256) void kv_pass(const unsigned short* __restrict__ qkv,
                                               const unsigned short* __restrict__ agg,
                                               float* __restrict__ kvpart) {
    const int h = blockIdx.x, b = blockIdx.y, c = blockIdx.z;
    const unsigned short* buf = (h < 32) ? qkv : agg;
    const int cbase = (h & 31) * 24;
    const u16x4* kp4 = (const u16x4*)(buf + ((size_t)b * 768 + cbase + 8)  * HW);
    const u16x4* vp4 = (const u16x4*)(buf + ((size_t)b * 768 + cbase + 16) * HW);

    const int nn = c * 256 + threadIdx.x;

    float kk[8][4];
#pragma unroll
    for (int d = 0; d < 8; d++) {
        u16x4 v = kp4[d * 1024 + nn];
        kk[d][0] = fmaxf(bf2f(v.x), 0.f); kk[d][1] = fmaxf(bf2f(v.y), 0.f);
        kk[d][2] = fmaxf(bf2f(v.z), 0.f); kk[d][3] = fmaxf(bf2f(v.w), 0.f);
    }

    float acc[8][9];
#pragma unroll
    for (int e = 0; e < 8; e++) {
        u16x4 vr = vp4[e * 1024 + nn];
        float v0 = bf2f(vr.x), v1 = bf2f(vr.y), v2 = bf2f(vr.z), v3 = bf2f(vr.w);
#pragma unroll
        for (int d = 0; d < 8; d++)
            acc[d][e] = kk[d][0] * v0 + kk[d][1] * v1 + kk[d][2] * v2 + kk[d][3] * v3;
    }
#pragma unroll
    for (int d = 0; d < 8; d++)
        acc[d][8] = kk[d][0] + kk[d][1] + kk[d][2] + kk[d][3];

    __shared__ float red[4][72];
    const int lane = threadIdx.x & 63, wv = threadIdx.x >> 6;
#pragma unroll
    for (int d = 0; d < 8; d++) {
#pragma unroll
        for (int e = 0; e < 9; e++) {
            float v = acc[d][e];
            v += __shfl_xor(v, 1);  v += __shfl_xor(v, 2);
            v += __shfl_xor(v, 4);  v += __shfl_xor(v, 8);
            v += __shfl_xor(v, 16); v += __shfl_xor(v, 32);
            if (lane == 0) red[wv][d * 9 + e] = v;
        }
    }
    __syncthreads();
    if (threadIdx.x < 72) {
        float s = red[0][threadIdx.x] + red[1][threadIdx.x] +
                  red[2][threadIdx.x] + red[3][threadIdx.x];
        kvpart[(size_t)c * 36864 + ((size_t)(b * 64 + h)) * 72 + threadIdx.x] = s;
    }
}

// ---------------- K3b: sum the 4 kv partial chunks ---------------------------
__global__ __launch_bounds__(256) void kv_red(const float* __restrict__ kvpart,
                                              float* __restrict__ kvout) {
    const int i = blockIdx.x * 256 + threadIdx.x;   // 144 blocks x 256 = 36864
    kvout[i] = (kvpart[i] + kvpart[36864 + i]) +
               (kvpart[2 * 36864 + i] + kvpart[3 * 36864 + i]);
}

// ---------------- K4: att -> att_f[b][h][n][8] (B-fragment-ready bf16) -------
// kv values are block-uniform: load once into registers from global (no LDS,
// no barrier).
__global__ __launch_bounds__(256) void att_pass(const unsigned short* __restrict__ qkv,
                                                const unsigned short* __restrict__ agg,
                                                const float* __restrict__ kvbuf,
                                                unsigned short* __restrict__ att_f) {
    const int h = blockIdx.y, b = blockIdx.z;
    const int t = threadIdx.x;
    const float* kvp = kvbuf + ((size_t)(b * 64 + h)) * 72;   // block-uniform

    float kvr[72];
#pragma unroll
    for (int i = 0; i < 18; i++) {
        f32x4 v = *(const f32x4*)&kvp[i * 4];
        kvr[i * 4 + 0] = v[0]; kvr[i * 4 + 1] = v[1];
        kvr[i * 4 + 2] = v[2]; kvr[i * 4 + 3] = v[3];
    }

    const unsigned short* buf = (h < 32) ? qkv : agg;
    const int cbase = (h & 31) * 24;
    const int n0 = (blockIdx.x * 256 + t) * 8;
    const unsigned short* qp = buf + ((size_t)b * 768 + cbase) * HW + n0;

    float q[8][8];
#pragma unroll
    for (int d = 0; d < 8; d++) {
        u16x8 v = *(const u16x8*)&qp[(size_t)d * HW];
#pragma unroll
        for (int j = 0; j < 8; j++) q[d][j] = fmaxf(bf2f(v[j]), 0.f);
    }

    unsigned short* op = att_f + (((size_t)(b * 64 + h)) * HW + n0) * 8;
#pragma unroll
    for (int j = 0; j < 8; j++) {
        float num[9];
#pragma unroll
        for (int e = 0; e < 9; e++) num[e] = 0.f;
#pragma unroll
        for (int d = 0; d < 8; d++) {
            const float qv = q[d][j];
#pragma unroll
            for (int e = 0; e < 9; e++) num[e] += qv * kvr[d * 9 + e];
        }
        const float rden = 1.f / (num[8] + ATT_EPS);
        u16x8 r;
#pragma unroll
        for (int e = 0; e < 8; e++) r[e] = (unsigned short)f2bf(num[e] * rden);
        *(u16x8*)&op[j * 8] = r;
    }
}

// ---------------- K5: p = Wp @ att, BN, +x — LDS-free direct-frag MFMA -------
__global__ __launch_bounds__(256) void proj_gemm(const unsigned short* __restrict__ wbf,
                                                 const unsigned short* __restrict__ att_f,
                                                 const float* __restrict__ gamma,
                                                 const float* __restrict__ beta,
                                                 const float* __restrict__ mean,
                                                 const float* __restrict__ var,
                                                 const float* __restrict__ x,
                                                 float* __restrict__ out) {
    const int t  = threadIdx.x;
    const int b  = blockIdx.z;
    const int ob = blockIdx.y * 128;
    const int nb = blockIdx.x * 128;
    const int lane = t & 63, wave = t >> 6;
    const int wo = (wave >> 1) * 64, wn = (wave & 1) * 64;

    const int am = lane & 15, ak = lane >> 4;
    const unsigned short* ap0 = wbf + (size_t)(ob + wo + am) * 512 + ak * 8;
    const unsigned short* bp0 = att_f +
        (((size_t)b * 64 + ak) * HW + nb + wn + am) * 8;

    f32x4 acc[4][4];
#pragma unroll
    for (int s = 0; s < 4; s++)
#pragma unroll
        for (int u = 0; u < 4; u++) acc[s][u] = (f32x4){0.f, 0.f, 0.f, 0.f};

    for (int kb = 0; kb < 512; kb += 32) {
        short8 af[4], bf[4];
#pragma unroll
        for (int s = 0; s < 4; s++)
            af[s] = *(const short8*)(ap0 + (size_t)s * 16 * 512 + kb);
#pragma unroll
        for (int u = 0; u < 4; u++)
            bf[u] = *(const short8*)(bp0 + ((size_t)(kb >> 3) * HW + u * 16) * 8);
#pragma unroll
        for (int s = 0; s < 4; s++)
#pragma unroll
            for (int u = 0; u < 4; u++)
                acc[s][u] = __builtin_amdgcn_mfma_f32_16x16x32_bf16(af[s], bf[u], acc[s][u], 0, 0, 0);
    }

#pragma unroll
    for (int s = 0; s < 4; s++) {
        const int o_base = ob + wo + s * 16 + (lane >> 4) * 4;
#pragma unroll
        for (int r = 0; r < 4; r++) {
            const int o = o_base + r;
            const float inv = gamma[o] * rsqrtf(var[o] + BN_EPS);
            const float sh  = beta[o] - mean[o] * inv;
#pragma unroll
            for (int u = 0; u < 4; u++) {
                const int n = nb + wn + u * 16 + (lane & 15);
                const size_t idx = ((size_t)b * 256 + o) * HW + n;
                out[idx] = x[idx] + acc[s][u][r] * inv + sh;
            }
        }
    }
}

extern "C" void kernel_launch(void* const* d_in, const int* in_sizes, int n_in,
                              void* d_out, int out_size, void* d_ws, size_t ws_size,
                              hipStream_t stream) {
    const float* x      = (const float*)d_in[0];
    const float* w_qkv  = (const float*)d_in[1];
    const float* w_dw   = (const float*)d_in[2];
    const float* w_pw   = (const float*)d_in[3];
    const float* w_proj = (const float*)d_in[4];
    const float* gamma  = (const float*)d_in[5];
    const float* beta   = (const float*)d_in[6];
    const float* mean   = (const float*)d_in[7];
    const float* var    = (const float*)d_in[8];
    float* out = (float*)d_out;

    unsigned short* qkv  = (unsigned short*)d_ws;      // 25165824 shorts
    unsigned short* agg  = qkv + (size_t)25165824;     // 25165824 shorts
    unsigned short* attf = agg + (size_t)25165824;     // 16777216 shorts
    unsigned short* wbf  = attf + (size_t)16777216;    // 131072 shorts
    float* kvb = (float*)(wbf + (size_t)131072);       // 36864 floats
    float* kvpart = (float*)attf;                      // 4*36864 f32, transient

    prep_w  <<<dim3(128),       256, 0, stream>>>(w_proj, wbf);
    qkv_gemm<<<dim3(32, 6, 8),  256, 0, stream>>>(x, w_qkv, qkv);
    dw_agg  <<<dim3(4, 96, 8),  256, 0, stream>>>(qkv, w_dw, w_pw, agg);
    kv_pass <<<dim3(64, 8, 4),  256, 0, stream>>>(qkv, agg, kvpart);
    kv_red  <<<dim3(144),       256, 0, stream>>>(kvpart, kvb);
    att_pass<<<dim3(2, 64, 8),  256, 0, stream>>>(qkv, agg, kvb, attf);
    proj_gemm<<<dim3(32, 2, 8), 256, 0, stream>>>(wbf, attf,
                                                  gamma, beta, mean, var, x, out);
}

// Round 7
// 220.796 us; speedup vs baseline: 1.1319x; 1.1319x over previous
//
#include <hip/hip_runtime.h>
#include <hip/hip_bf16.h>

// LiteMLA: B=8, C=256, H=W=64, N=HW=4096, td=256, d=8, heads=64
// ws: qkv bf16 (8,768,4096) | agg bf16 (8,768,4096) | att_f bf16 (8,64,4096,8)
//     | w_projbf bf16 (256,512) | kvb f32 (8,64,72)
// kv partials (16 chunks x 36864 f32) live in the att_f region (written later).
// Pipeline: prep_w, qkv_gemm (MFMA), dw_agg (split-ch f32 LDS, scalar-pipe
//           weights), kv_pass (MFMA head-pair, no shuffles), kv_red,
//           att_pass (reg-kv), proj_gemm (LDS-free MFMA)

#define HW 4096
#define ATT_EPS 1e-15f
#define BN_EPS 1e-6f

typedef __attribute__((ext_vector_type(8))) short short8;
typedef __attribute__((ext_vector_type(4))) short short4v;
typedef __attribute__((ext_vector_type(4))) float f32x4;
typedef __attribute__((ext_vector_type(2))) float f32x2;
typedef __attribute__((ext_vector_type(8))) unsigned short u16x8;
typedef __attribute__((ext_vector_type(4))) unsigned short u16x4;

static __device__ inline short f2bf(float f) {
    union { float f; unsigned u; } v; v.f = f;
    unsigned r = v.u + 0x7fff + ((v.u >> 16) & 1);   // RNE, finite inputs
    return (short)(r >> 16);
}
static __device__ inline float bf2f(unsigned short u) {
    union { unsigned u; float f; } v; v.u = (unsigned)u << 16; return v.f;
}

// ---------------- K0: w_proj f32 -> bf16 (256x512) ----------------
__global__ __launch_bounds__(256) void prep_w(const float* __restrict__ wproj,
                                              unsigned short* __restrict__ wbf) {
    const int i = (blockIdx.x * 256 + threadIdx.x) * 4;
    float4 v = *(const float4*)&wproj[i];
    u16x4 r = {(unsigned short)f2bf(v.x), (unsigned short)f2bf(v.y),
               (unsigned short)f2bf(v.z), (unsigned short)f2bf(v.w)};
    *(u16x4*)&wbf[i] = r;
}

// ---------------- K1: qkv(bf16) = W(768x256) @ X(256x4096), bf16 MFMA --------
__global__ __launch_bounds__(256) void qkv_gemm(const float* __restrict__ x,
                                                const float* __restrict__ w,
                                                unsigned short* __restrict__ qkv) {
    __shared__ short A_l[128 * 40];
    __shared__ short B_l[128 * 40];
    const int t  = threadIdx.x;
    const int b  = blockIdx.z;
    const int ob = blockIdx.y * 128;
    const int nb = blockIdx.x * 128;
    const float* xb = x + (size_t)b * 256 * HW;

    const int lane = t & 63, wave = t >> 6;
    const int wo = (wave >> 1) * 64, wn = (wave & 1) * 64;

    f32x4 acc[4][4];
#pragma unroll
    for (int s = 0; s < 4; s++)
#pragma unroll
        for (int u = 0; u < 4; u++) acc[s][u] = (f32x4){0.f, 0.f, 0.f, 0.f};

    const int col4 = (t & 7) * 4;
    const int r0   = t >> 3;            // 0..31
    for (int kb = 0; kb < 256; kb += 32) {
        __syncthreads();
#pragma unroll
        for (int i = 0; i < 4; i++) {
            const int r = r0 + 32 * i;
            float4 v = *(const float4*)&w[(ob + r) * 256 + kb + col4];
            short4v s4 = {f2bf(v.x), f2bf(v.y), f2bf(v.z), f2bf(v.w)};
            *(short4v*)&A_l[r * 40 + col4] = s4;
        }
#pragma unroll
        for (int i = 0; i < 4; i++) {
            const int n4 = (t & 7) + 8 * i;
            float4 v = *(const float4*)&xb[(size_t)(kb + r0) * HW + nb + n4 * 4];
            B_l[(n4 * 4 + 0) * 40 + r0] = f2bf(v.x);
            B_l[(n4 * 4 + 1) * 40 + r0] = f2bf(v.y);
            B_l[(n4 * 4 + 2) * 40 + r0] = f2bf(v.z);
            B_l[(n4 * 4 + 3) * 40 + r0] = f2bf(v.w);
        }
        __syncthreads();

        short8 af[4], bf[4];
#pragma unroll
        for (int s = 0; s < 4; s++)
            af[s] = *(const short8*)&A_l[(wo + s * 16 + (lane & 15)) * 40 + (lane >> 4) * 8];
#pragma unroll
        for (int u = 0; u < 4; u++)
            bf[u] = *(const short8*)&B_l[(wn + u * 16 + (lane & 15)) * 40 + (lane >> 4) * 8];
#pragma unroll
        for (int s = 0; s < 4; s++)
#pragma unroll
            for (int u = 0; u < 4; u++)
                acc[s][u] = __builtin_amdgcn_mfma_f32_16x16x32_bf16(af[s], bf[u], acc[s][u], 0, 0, 0);
    }

#pragma unroll
    for (int s = 0; s < 4; s++)
#pragma unroll
        for (int u = 0; u < 4; u++)
#pragma unroll
            for (int r = 0; r < 4; r++) {
                const int o = ob + wo + s * 16 + (lane >> 4) * 4 + r;
                const int n = nb + wn + u * 16 + (lane & 15);
                qkv[((size_t)b * 768 + o) * HW + n] = (unsigned short)f2bf(acc[s][u][r]);
            }
}

// ---------------- K2: fused dw5x5 + pw8x8 ------------------------------------
// grid (4 ytiles(16 rows), 96 g, 8 b), block 256. Thread: 1 row x 4 col.
// Weights via block-uniform global pointers -> scalar pipe (R5 win: zero LDS
// traffic for weights). Tile f32 [4ch][20r][64c] split 2x with refill
// (20.7 KB -> 6 blocks/CU). Accumulator out[8][4] = 32 f32 (R2: bigger spills).
__global__ __launch_bounds__(256, 6) void dw_agg(const unsigned short* __restrict__ qkv,
                                                 const float* __restrict__ wdw,
                                                 const float* __restrict__ wpw,
                                                 unsigned short* __restrict__ agg) {
    __shared__ float tile_raw[8 + 4 * 20 * 64 + 8];   // 20.7 KB
    float* tile = tile_raw + 8;
    const int b = blockIdx.z, g = blockIdx.y;
    const int y0 = blockIdx.x * 16;
    const int t = threadIdx.x;
    const int tx = t & 15, ty = t >> 4;     // col-quad, output row

    const float* wkg = wdw + g * 8 * 25;    // block-uniform -> scalar loads
    const float* pwg = wpw + g * 64;        // block-uniform -> scalar loads

    float out[8][4];
#pragma unroll
    for (int o = 0; o < 8; o++)
#pragma unroll
        for (int j = 0; j < 4; j++) out[o][j] = 0.f;

#pragma unroll 1
    for (int half = 0; half < 2; half++) {
        if (half) __syncthreads();          // all reads of prev half done
        // fill: 640 octet-slots (4ch x 20r x 8 col-octets); bf16->f32 once.
#pragma unroll
        for (int k = 0; k < 3; k++) {
            const int i = t + 256 * k;
            if (i < 640) {
                const int c8 = i & 7, rr = (i >> 3) % 20, ch = i / 160;
                const int y = y0 - 2 + rr;
                u16x8 v = {0, 0, 0, 0, 0, 0, 0, 0};
                if (y >= 0 && y < 64)
                    v = *(const u16x8*)&qkv[((size_t)(b * 768 + g * 8 + half * 4 + ch)) * HW + y * 64 + c8 * 8];
                f32x4 lo = {bf2f(v[0]), bf2f(v[1]), bf2f(v[2]), bf2f(v[3])};
                f32x4 hi = {bf2f(v[4]), bf2f(v[5]), bf2f(v[6]), bf2f(v[7])};
                *(f32x4*)&tile[i * 8]     = lo;
                *(f32x4*)&tile[i * 8 + 4] = hi;
            }
        }
        __syncthreads();

#pragma unroll 1
        for (int ch4 = 0; ch4 < 4; ch4++) {
            const int ch = half * 4 + ch4;
            const float* wkc = wkg + ch * 25;    // uniform -> SGPR
            float a0 = 0.f, a1 = 0.f, a2 = 0.f, a3 = 0.f;
#pragma unroll
            for (int dy = 0; dy < 5; dy++) {
                const int off = ch4 * 1280 + (ty + dy) * 64 + tx * 4;
                f32x4 C = *(const f32x4*)&tile[off];        // ds_read_b128
                f32x2 L = *(const f32x2*)&tile[off - 2];    // ds_read_b64
                f32x2 R = *(const f32x2*)&tile[off + 4];    // ds_read_b64
                float win[8];
                win[0] = (tx == 0)  ? 0.f : L[0];
                win[1] = (tx == 0)  ? 0.f : L[1];
                win[2] = C[0]; win[3] = C[1];
                win[4] = C[2]; win[5] = C[3];
                win[6] = (tx == 15) ? 0.f : R[0];
                win[7] = (tx == 15) ? 0.f : R[1];
#pragma unroll
                for (int dx = 0; dx < 5; dx++) {
                    const float wv = wkc[dy * 5 + dx];      // SGPR operand
                    a0 += wv * win[dx + 0];
                    a1 += wv * win[dx + 1];
                    a2 += wv * win[dx + 2];
                    a3 += wv * win[dx + 3];
                }
            }
#pragma unroll
            for (int o = 0; o < 8; o++) {
                const float wv = pwg[o * 8 + ch];           // SGPR operand
                out[o][0] += wv * a0; out[o][1] += wv * a1;
                out[o][2] += wv * a2; out[o][3] += wv * a3;
            }
        }
    }

#pragma unroll
    for (int o = 0; o < 8; o++) {
        u16x4 rv = {(unsigned short)f2bf(out[o][0]), (unsigned short)f2bf(out[o][1]),
                    (unsigned short)f2bf(out[o][2]), (unsigned short)f2bf(out[o][3])};
        *(u16x4*)&agg[((size_t)(b * 768 + g * 8 + o)) * HW + (y0 + ty) * 64 + tx * 4] = rv;
    }
}

// ---------------- K3: kv partials via MFMA (head-pair per wave) --------------
// R6 lesson: the 72x6 __shfl_xor butterfly (432 cross-lane ops/thread) was the
// kernel, not the streaming. kv[d][e] = sum_n relu(k[n,d]) v[n,e] is a
// 16x16x4096 GEMM: A rows 0-7 = relu(K) of h0, rows 8-15 = h1; two B frags
// (V0pad, V1pad; col 8 = bf16 1.0 -> ksum via ones-column; cols 9-15 = 0);
// keep diagonal output blocks. No shuffles, no LDS, no barriers.
// grid (8 hp-quads, 8 b, 16 n-chunks), block 256 = 4 waves; 8 unrolled
// 32-n MFMA steps per wave.
__global__ __launch_bounds__(256) void kv_pass(const unsigned short* __restrict__ qkv,
                                               const unsigned short* __restrict__ agg,
                                               float* __restrict__ kvpart) {
    const int t = threadIdx.x;
    const int w = t >> 6, lane = t & 63;
    const int hp = blockIdx.x * 4 + w;          // head-pair 0..31
    const int b = blockIdx.y, c = blockIdx.z;   // batch, n-chunk
    const int h0 = hp * 2, h1 = h0 + 1;         // same buf half always
    const unsigned short* buf = (h0 < 32) ? qkv : agg;
    const int cb0 = (h0 & 31) * 24, cb1 = (h1 & 31) * 24;

    const int row = lane & 15, kgrp = lane >> 4;
    const int n0 = c * 256 + kgrp * 8;

    // A: rows 0-7 -> h0 k-dims, rows 8-15 -> h1 k-dims (cb1 + row == cb1+8+(row-8))
    const int chA = (row < 8) ? (cb0 + 8 + row) : (cb1 + row);
    const unsigned short* ap = buf + ((size_t)b * 768 + chA) * HW + n0;

    // B: col = row; cols 0-7 load v-channels, col 8 = ones, cols 9-15 = 0
    const bool bload = (row < 8);
    const unsigned short* bp0 = buf + ((size_t)b * 768 + cb0 + 16 + (row & 7)) * HW + n0;
    const unsigned short* bp1 = buf + ((size_t)b * 768 + cb1 + 16 + (row & 7)) * HW + n0;
    const short cfill = (row == 8) ? (short)0x3F80 : (short)0;   // bf16 1.0
    const short8 bconst = {cfill, cfill, cfill, cfill, cfill, cfill, cfill, cfill};

    f32x4 acc0 = {0.f, 0.f, 0.f, 0.f};
    f32x4 acc1 = {0.f, 0.f, 0.f, 0.f};

#pragma unroll
    for (int i = 0; i < 8; i++) {
        u16x8 av = *(const u16x8*)(ap + i * 32);
        short8 b0 = bload ? *(const short8*)(bp0 + i * 32) : bconst;
        short8 b1 = bload ? *(const short8*)(bp1 + i * 32) : bconst;
        short8 ar;
#pragma unroll
        for (int j = 0; j < 8; j++)
            ar[j] = (short)((av[j] & 0x8000) ? 0 : av[j]);    // relu on bf16 bits
        acc0 = __builtin_amdgcn_mfma_f32_16x16x32_bf16(ar, b0, acc0, 0, 0, 0);
        acc1 = __builtin_amdgcn_mfma_f32_16x16x32_bf16(ar, b1, acc1, 0, 0, 0);
    }

    // C layout: col = lane&15, out_row = kgrp*4+r. acc0 rows 0-7 = kv_h0,
    // acc1 rows 8-15 = kv_h1. Valid cols: 0..8.
    if (row <= 8) {
        float* kp;
        f32x4 a;
        int dbase;
        if (kgrp < 2) {
            kp = kvpart + (size_t)c * 36864 + (size_t)(b * 64 + h0) * 72;
            a = acc0; dbase = kgrp * 4;
        } else {
            kp = kvpart + (size_t)c * 36864 + (size_t)(b * 64 + h1) * 72;
            a = acc1; dbase = (kgrp - 2) * 4;
        }
#pragma unroll
        for (int r = 0; r < 4; r++)
            kp[(dbase + r) * 9 + row] = a[r];
    }
}

// ---------------- K3b: sum the 16 kv partial chunks --------------------------
__global__ __launch_bounds__(256) void kv_red(const float* __restrict__ kvpart,
                                              float* __restrict__ kvout) {
    const int i = blockIdx.x * 256 + threadIdx.x;   // 144 blocks x 256 = 36864
    float s = 0.f;
#pragma unroll
    for (int c = 0; c < 16; c++) s += kvpart[(size_t)c * 36864 + i];
    kvout[i] = s;
}

// ---------------- K4: att -> att_f[b][h][n][8] (B-fragment-ready bf16) -------
// kv values are block-uniform: load once into registers from global (no LDS,
// no barrier).
__global__ __launch_bounds__(256) void att_pass(const unsigned short* __restrict__ qkv,
                                                const unsigned short* __restrict__ agg,
                                                const float* __restrict__ kvbuf,
                                                unsigned short* __restrict__ att_f) {
    const int h = blockIdx.y, b = blockIdx.z;
    const int t = threadIdx.x;
    const float* kvp = kvbuf + ((size_t)(b * 64 + h)) * 72;   // block-uniform

    float kvr[72];
#pragma unroll
    for (int i = 0; i < 18; i++) {
        f32x4 v = *(const f32x4*)&kvp[i * 4];
        kvr[i * 4 + 0] = v[0]; kvr[i * 4 + 1] = v[1];
        kvr[i * 4 + 2] = v[2]; kvr[i * 4 + 3] = v[3];
    }

    const unsigned short* buf = (h < 32) ? qkv : agg;
    const int cbase = (h & 31) * 24;
    const int n0 = (blockIdx.x * 256 + t) * 8;
    const unsigned short* qp = buf + ((size_t)b * 768 + cbase) * HW + n0;

    float q[8][8];
#pragma unroll
    for (int d = 0; d < 8; d++) {
        u16x8 v = *(const u16x8*)&qp[(size_t)d * HW];
#pragma unroll
        for (int j = 0; j < 8; j++) q[d][j] = fmaxf(bf2f(v[j]), 0.f);
    }

    unsigned short* op = att_f + (((size_t)(b * 64 + h)) * HW + n0) * 8;
#pragma unroll
    for (int j = 0; j < 8; j++) {
        float num[9];
#pragma unroll
        for (int e = 0; e < 9; e++) num[e] = 0.f;
#pragma unroll
        for (int d = 0; d < 8; d++) {
            const float qv = q[d][j];
#pragma unroll
            for (int e = 0; e < 9; e++) num[e] += qv * kvr[d * 9 + e];
        }
        const float rden = 1.f / (num[8] + ATT_EPS);
        u16x8 r;
#pragma unroll
        for (int e = 0; e < 8; e++) r[e] = (unsigned short)f2bf(num[e] * rden);
        *(u16x8*)&op[j * 8] = r;
    }
}

// ---------------- K5: p = Wp @ att, BN, +x — LDS-free direct-frag MFMA -------
__global__ __launch_bounds__(256) void proj_gemm(const unsigned short* __restrict__ wbf,
                                                 const unsigned short* __restrict__ att_f,
                                                 const float* __restrict__ gamma,
                                                 const float* __restrict__ beta,
                                                 const float* __restrict__ mean,
                                                 const float* __restrict__ var,
                                                 const float* __restrict__ x,
                                                 float* __restrict__ out) {
    const int t  = threadIdx.x;
    const int b  = blockIdx.z;
    const int ob = blockIdx.y * 128;
    const int nb = blockIdx.x * 128;
    const int lane = t & 63, wave = t >> 6;
    const int wo = (wave >> 1) * 64, wn = (wave & 1) * 64;

    const int am = lane & 15, ak = lane >> 4;
    const unsigned short* ap0 = wbf + (size_t)(ob + wo + am) * 512 + ak * 8;
    const unsigned short* bp0 = att_f +
        (((size_t)b * 64 + ak) * HW + nb + wn + am) * 8;

    f32x4 acc[4][4];
#pragma unroll
    for (int s = 0; s < 4; s++)
#pragma unroll
        for (int u = 0; u < 4; u++) acc[s][u] = (f32x4){0.f, 0.f, 0.f, 0.f};

    for (int kb = 0; kb < 512; kb += 32) {
        short8 af[4], bf[4];
#pragma unroll
        for (int s = 0; s < 4; s++)
            af[s] = *(const short8*)(ap0 + (size_t)s * 16 * 512 + kb);
#pragma unroll
        for (int u = 0; u < 4; u++)
            bf[u] = *(const short8*)(bp0 + ((size_t)(kb >> 3) * HW + u * 16) * 8);
#pragma unroll
        for (int s = 0; s < 4; s++)
#pragma unroll
            for (int u = 0; u < 4; u++)
                acc[s][u] = __builtin_amdgcn_mfma_f32_16x16x32_bf16(af[s], bf[u], acc[s][u], 0, 0, 0);
    }

#pragma unroll
    for (int s = 0; s < 4; s++) {
        const int o_base = ob + wo + s * 16 + (lane >> 4) * 4;
#pragma unroll
        for (int r = 0; r < 4; r++) {
            const int o = o_base + r;
            const float inv = gamma[o] * rsqrtf(var[o] + BN_EPS);
            const float sh  = beta[o] - mean[o] * inv;
#pragma unroll
            for (int u = 0; u < 4; u++) {
                const int n = nb + wn + u * 16 + (lane & 15);
                const size_t idx = ((size_t)b * 256 + o) * HW + n;
                out[idx] = x[idx] + acc[s][u][r] * inv + sh;
            }
        }
    }
}

extern "C" void kernel_launch(void* const* d_in, const int* in_sizes, int n_in,
                              void* d_out, int out_size, void* d_ws, size_t ws_size,
                              hipStream_t stream) {
    const float* x      = (const float*)d_in[0];
    const float* w_qkv  = (const float*)d_in[1];
    const float* w_dw   = (const float*)d_in[2];
    const float* w_pw   = (const float*)d_in[3];
    const float* w_proj = (const float*)d_in[4];
    const float* gamma  = (const float*)d_in[5];
    const float* beta   = (const float*)d_in[6];
    const float* mean   = (const float*)d_in[7];
    const float* var    = (const float*)d_in[8];
    float* out = (float*)d_out;

    unsigned short* qkv  = (unsigned short*)d_ws;      // 25165824 shorts
    unsigned short* agg  = qkv + (size_t)25165824;     // 25165824 shorts
    unsigned short* attf = agg + (size_t)25165824;     // 16777216 shorts
    unsigned short* wbf  = attf + (size_t)16777216;    // 131072 shorts
    float* kvb = (float*)(wbf + (size_t)131072);       // 36864 floats
    float* kvpart = (float*)attf;                      // 16*36864 f32, transient

    prep_w  <<<dim3(128),       256, 0, stream>>>(w_proj, wbf);
    qkv_gemm<<<dim3(32, 6, 8),  256, 0, stream>>>(x, w_qkv, qkv);
    dw_agg  <<<dim3(4, 96, 8),  256, 0, stream>>>(qkv, w_dw, w_pw, agg);
    kv_pass <<<dim3(8, 8, 16),  256, 0, stream>>>(qkv, agg, kvpart);
    kv_red  <<<dim3(144),       256, 0, stream>>>(kvpart, kvb);
    att_pass<<<dim3(2, 64, 8),  256, 0, stream>>>(qkv, agg, kvb, attf);
    proj_gemm<<<dim3(32, 2, 8), 256, 0, stream>>>(wbf, attf,
                                                  gamma, beta, mean, var, x, out);
}